// Round 1
// baseline (6308.484 us; speedup 1.0000x reference)
//
#include <hip/hip_runtime.h>
#include <math.h>

#define N_NODES 50000
#define N_EDGES 1000000
#define LAYERS  3
#define G_GRAPHS 512
#define H 128
#define NG 50
#define PI_F 3.14159265358979323846f
#define LOG2_F 0.6931471805599453f

__device__ __forceinline__ float ssp(float v) {
    // softplus(x) - log(2), numerically stable
    return fmaxf(v, 0.0f) + log1pf(expf(-fabsf(v))) - LOG2_F;
}

// -------------------- h = relu(emb[z]) --------------------
__global__ __launch_bounds__(256) void init_h(const int* __restrict__ z,
                                              const float* __restrict__ emb,
                                              float* __restrict__ h) {
    int idx = blockIdx.x * 256 + threadIdx.x;          // over N*(H/4)
    if (idx >= N_NODES * (H / 4)) return;
    int n = idx >> 5;                                  // H/4 == 32
    int c4 = idx & 31;
    int zv = z[n];
    float4 v = *(const float4*)(emb + (size_t)zv * H + c4 * 4);
    v.x = fmaxf(v.x, 0.f); v.y = fmaxf(v.y, 0.f);
    v.z = fmaxf(v.z, 0.f); v.w = fmaxf(v.w, 0.f);
    *(float4*)(h + (size_t)n * H + c4 * 4) = v;
}

// -------------------- generic node GEMM: Out[n, :NC] (op) A[n,:128] @ B[128,NC] --------------------
#define F_BIAS 1
#define F_SSPA 2
#define F_ACCUM 4
#define F_POOL 8

template <int FLAGS>
__global__ __launch_bounds__(256) void node_gemm(const float* __restrict__ A,
                                                 const float* __restrict__ B,
                                                 const float* __restrict__ bias,
                                                 float* __restrict__ Out,
                                                 const int* __restrict__ batch,
                                                 int nRows, int NC) {
    __shared__ float At[64 * 132];     // A tile, row-major, ld 132
    __shared__ float Bc[32 * 128];     // B k-chunk
    int tid = threadIdx.x;
    int rowBase = blockIdx.x * 64;
    int colOff = blockIdx.y * 128;
    int rlim = nRows - rowBase; if (rlim > 64) rlim = 64;

    // stage A tile (ssp on load if requested)
    for (int idx4 = tid; idx4 < 2048; idx4 += 256) {
        int r = idx4 >> 5, k4 = idx4 & 31;
        float4 v = make_float4(0.f, 0.f, 0.f, 0.f);
        if (r < rlim) {
            v = *(const float4*)(A + (size_t)(rowBase + r) * H + k4 * 4);
            if (FLAGS & F_SSPA) { v.x = ssp(v.x); v.y = ssp(v.y); v.z = ssp(v.z); v.w = ssp(v.w); }
        }
        *(float4*)(At + r * 132 + k4 * 4) = v;
    }

    int cg = tid & 15, rg = tid >> 4;
    int r0 = rg * 4;
    int lc0 = cg * 4, lc1 = 64 + cg * 4;          // local cols in the 128-wide tile
    int gc0 = colOff + lc0, gc1 = colOff + lc1;   // global cols

    float acc[4][8];
#pragma unroll
    for (int j = 0; j < 4; ++j) {
        float b0 = 0.f, b1v = 0.f;
        if (FLAGS & F_BIAS) { b0 = bias[gc0 + j]; b1v = bias[gc1 + j]; }
#pragma unroll
        for (int i = 0; i < 4; ++i) { acc[i][j] = b0; acc[i][4 + j] = b1v; }
    }

    for (int kc = 0; kc < 4; ++kc) {
        __syncthreads();
        for (int idx4 = tid; idx4 < 1024; idx4 += 256) {
            int r = idx4 >> 5, c4 = idx4 & 31;
            *(float4*)(Bc + r * 128 + c4 * 4) =
                *(const float4*)(B + (size_t)(kc * 32 + r) * NC + colOff + c4 * 4);
        }
        __syncthreads();
        for (int kk = 0; kk < 32; ++kk) {
            int k = kc * 32 + kk;
            float a0 = At[(r0 + 0) * 132 + k];
            float a1 = At[(r0 + 1) * 132 + k];
            float a2 = At[(r0 + 2) * 132 + k];
            float a3 = At[(r0 + 3) * 132 + k];
            float4 w0 = *(float4*)(Bc + kk * 128 + lc0);
            float4 w1 = *(float4*)(Bc + kk * 128 + lc1);
            float av[4] = {a0, a1, a2, a3};
            float wv[8] = {w0.x, w0.y, w0.z, w0.w, w1.x, w1.y, w1.z, w1.w};
#pragma unroll
            for (int i = 0; i < 4; ++i)
#pragma unroll
                for (int j = 0; j < 8; ++j) acc[i][j] = fmaf(av[i], wv[j], acc[i][j]);
        }
    }

    if (FLAGS & F_POOL) {
        // ssp, then segment-pool into Out[batch[r], :] with run compaction (batch sorted)
        int cur = -1;
        float sA[4] = {0, 0, 0, 0}, sB[4] = {0, 0, 0, 0};
#pragma unroll
        for (int i = 0; i < 4; ++i) {
            int r = r0 + i;
            int b = (r < rlim) ? batch[rowBase + r] : -1;
            if (b != cur) {
                if (cur >= 0) {
#pragma unroll
                    for (int j = 0; j < 4; ++j) {
                        unsafeAtomicAdd(Out + (size_t)cur * NC + gc0 + j, sA[j]);
                        unsafeAtomicAdd(Out + (size_t)cur * NC + gc1 + j, sB[j]);
                    }
                }
                cur = b;
#pragma unroll
                for (int j = 0; j < 4; ++j) { sA[j] = 0.f; sB[j] = 0.f; }
            }
            if (b >= 0) {
#pragma unroll
                for (int j = 0; j < 4; ++j) {
                    sA[j] += ssp(acc[i][j]);
                    sB[j] += ssp(acc[i][4 + j]);
                }
            }
        }
        if (cur >= 0) {
#pragma unroll
            for (int j = 0; j < 4; ++j) {
                unsafeAtomicAdd(Out + (size_t)cur * NC + gc0 + j, sA[j]);
                unsafeAtomicAdd(Out + (size_t)cur * NC + gc1 + j, sB[j]);
            }
        }
    } else {
#pragma unroll
        for (int i = 0; i < 4; ++i) {
            int r = r0 + i;
            if (r >= rlim) break;
            float* orow = Out + (size_t)(rowBase + r) * NC;
            float4 vA = make_float4(acc[i][0], acc[i][1], acc[i][2], acc[i][3]);
            float4 vB = make_float4(acc[i][4], acc[i][5], acc[i][6], acc[i][7]);
            if (FLAGS & F_ACCUM) {
                float4 oA = *(float4*)(orow + gc0);
                float4 oB = *(float4*)(orow + gc1);
                vA.x += oA.x; vA.y += oA.y; vA.z += oA.z; vA.w += oA.w;
                vB.x += oB.x; vB.y += oB.y; vB.z += oB.z; vB.w += oB.w;
            }
            *(float4*)(orow + gc0) = vA;
            *(float4*)(orow + gc1) = vB;
        }
    }
}

// -------------------- fused edge kernel --------------------
// Wf = (ssp(attr@W1 + b1) @ W2 + b2) * C;  agg[dst] += x[src] * Wf
__global__ __launch_bounds__(256) void edge_kernel(const float* __restrict__ eattr,
                                                   const float* __restrict__ ew,
                                                   const int* __restrict__ esrc,
                                                   const int* __restrict__ edst,
                                                   const float* __restrict__ W1,
                                                   const float* __restrict__ b1,
                                                   const float* __restrict__ W2,
                                                   const float* __restrict__ b2,
                                                   const float* __restrict__ x,
                                                   float* __restrict__ agg) {
    __shared__ float bufA[9800];       // phase1: attrT[50][68] + W1s[50*128]; phase2: Tt[128][68]
    __shared__ float W2c[32 * 128];    // W2 k-chunk
    __shared__ float Ce[64];
    __shared__ int Se[64], De[64];
    float* attrT = bufA;
    float* W1s = bufA + 3400;
    float* Tt = bufA;

    int tid = threadIdx.x;
    int e0 = blockIdx.x * 64;

    for (int idx = tid; idx < 64 * NG; idx += 256) {
        int e = idx / NG, k = idx - e * NG;
        attrT[k * 68 + e] = eattr[(size_t)(e0 + e) * NG + k];
    }
    for (int idx = tid; idx < NG * H; idx += 256) W1s[idx] = W1[idx];
    if (tid < 64) {
        int e = e0 + tid;
        Ce[tid] = 0.5f * (cosf(ew[e] * (PI_F / 10.0f)) + 1.0f);
        Se[tid] = esrc[e];
        De[tid] = edst[e];
    }
    __syncthreads();

    int cg = tid & 15, rg = tid >> 4;
    int el = rg * 4;                   // 4 edges
    int c0 = cg * 4, c1 = 64 + cg * 4; // 8 cols (split halves: 2-way LDS banks = free)

    // ---- GEMM1: T = ssp(attr @ W1 + b1) ----
    float acc[4][8];
#pragma unroll
    for (int j = 0; j < 4; ++j) {
        float bj0 = b1[c0 + j], bj1 = b1[c1 + j];
#pragma unroll
        for (int i = 0; i < 4; ++i) { acc[i][j] = bj0; acc[i][4 + j] = bj1; }
    }
    for (int k = 0; k < NG; ++k) {
        float4 av = *(float4*)(attrT + k * 68 + el);
        float4 w0 = *(float4*)(W1s + k * H + c0);
        float4 w1 = *(float4*)(W1s + k * H + c1);
        float avf[4] = {av.x, av.y, av.z, av.w};
        float wv[8] = {w0.x, w0.y, w0.z, w0.w, w1.x, w1.y, w1.z, w1.w};
#pragma unroll
        for (int i = 0; i < 4; ++i)
#pragma unroll
            for (int j = 0; j < 8; ++j) acc[i][j] = fmaf(avf[i], wv[j], acc[i][j]);
    }
    __syncthreads();   // done reading attrT/W1s; Tt overlays them
#pragma unroll
    for (int j = 0; j < 8; ++j) {
        int c = (j < 4) ? (c0 + j) : (c1 + j - 4);
        float4 tv = make_float4(ssp(acc[0][j]), ssp(acc[1][j]), ssp(acc[2][j]), ssp(acc[3][j]));
        *(float4*)(Tt + c * 68 + el) = tv;
    }

    // ---- GEMM2: Wf = T @ W2 + b2 (W2 staged in 32-row chunks) ----
    float acc2[4][8];
#pragma unroll
    for (int j = 0; j < 4; ++j) {
        float bj0 = b2[c0 + j], bj1 = b2[c1 + j];
#pragma unroll
        for (int i = 0; i < 4; ++i) { acc2[i][j] = bj0; acc2[i][4 + j] = bj1; }
    }
    for (int kc = 0; kc < 4; ++kc) {
        __syncthreads();   // Tt writes visible (kc=0); prev chunk consumed (kc>0)
        for (int idx4 = tid; idx4 < 1024; idx4 += 256) {
            int r = idx4 >> 5, c4 = idx4 & 31;
            *(float4*)(W2c + r * H + c4 * 4) =
                *(const float4*)(W2 + (size_t)(kc * 32 + r) * H + c4 * 4);
        }
        __syncthreads();
        for (int kk = 0; kk < 32; ++kk) {
            float4 tv = *(float4*)(Tt + (kc * 32 + kk) * 68 + el);
            float4 w0 = *(float4*)(W2c + kk * H + c0);
            float4 w1 = *(float4*)(W2c + kk * H + c1);
            float tvf[4] = {tv.x, tv.y, tv.z, tv.w};
            float wv[8] = {w0.x, w0.y, w0.z, w0.w, w1.x, w1.y, w1.z, w1.w};
#pragma unroll
            for (int i = 0; i < 4; ++i)
#pragma unroll
                for (int j = 0; j < 8; ++j) acc2[i][j] = fmaf(tvf[i], wv[j], acc2[i][j]);
        }
    }

    // ---- epilogue: msg = x[src] * Wf * C -> atomic scatter to agg[dst] ----
#pragma unroll
    for (int i = 0; i < 4; ++i) {
        int le = el + i;
        float cf = Ce[le];
        int s = Se[le], d = De[le];
        float4 xa = *(const float4*)(x + (size_t)s * H + c0);
        float4 xb = *(const float4*)(x + (size_t)s * H + c1);
        float* ag = agg + (size_t)d * H;
        unsafeAtomicAdd(ag + c0 + 0, xa.x * acc2[i][0] * cf);
        unsafeAtomicAdd(ag + c0 + 1, xa.y * acc2[i][1] * cf);
        unsafeAtomicAdd(ag + c0 + 2, xa.z * acc2[i][2] * cf);
        unsafeAtomicAdd(ag + c0 + 3, xa.w * acc2[i][3] * cf);
        unsafeAtomicAdd(ag + c1 + 0, xb.x * acc2[i][4] * cf);
        unsafeAtomicAdd(ag + c1 + 1, xb.y * acc2[i][5] * cf);
        unsafeAtomicAdd(ag + c1 + 2, xb.z * acc2[i][6] * cf);
        unsafeAtomicAdd(ag + c1 + 3, xb.w * acc2[i][7] * cf);
    }
}

// -------------------- out = ssp(pooled@ro_w2 + b2) @ ro_w3 + b3 --------------------
__global__ __launch_bounds__(128) void final_out(const float* __restrict__ pooled,
                                                 const float* __restrict__ ro_w2,
                                                 const float* __restrict__ ro_b2,
                                                 const float* __restrict__ ro_w3,
                                                 const float* __restrict__ ro_b3,
                                                 float* __restrict__ out) {
    int g = blockIdx.x;
    int c = threadIdx.x;     // 128
    float acc = ro_b2[c];
    const float* pr = pooled + (size_t)g * (5 * H);
    for (int k = 0; k < 5 * H; ++k) acc = fmaf(pr[k], ro_w2[(size_t)k * H + c], acc);
    float v = ssp(acc) * ro_w3[c];
    __shared__ float red[128];
    red[c] = v;
    __syncthreads();
    for (int s = 64; s > 0; s >>= 1) {
        if (c < s) red[c] += red[c + s];
        __syncthreads();
    }
    if (c == 0) out[g] = red[0] + ro_b3[0];
}

extern "C" void kernel_launch(void* const* d_in, const int* in_sizes, int n_in,
                              void* d_out, int out_size, void* d_ws, size_t ws_size,
                              hipStream_t stream) {
    const int* z     = (const int*)d_in[0];
    const int* esrc  = (const int*)d_in[1];
    const int* edst  = (const int*)d_in[2];
    const int* batch = (const int*)d_in[3];
    const float* ew    = (const float*)d_in[5];
    const float* eattr = (const float*)d_in[6];
    const float* emb   = (const float*)d_in[7];
    const float* mlp_w1 = (const float*)d_in[8];
    const float* mlp_b1 = (const float*)d_in[9];
    const float* mlp_w2 = (const float*)d_in[10];
    const float* mlp_b2 = (const float*)d_in[11];
    const float* cf_w1  = (const float*)d_in[12];
    const float* cf_w2  = (const float*)d_in[13];
    const float* cf_b2  = (const float*)d_in[14];
    const float* lin_w  = (const float*)d_in[15];
    const float* lin_b  = (const float*)d_in[16];
    const float* ro_w1  = (const float*)d_in[17];
    const float* ro_b1  = (const float*)d_in[18];
    const float* ro_w2  = (const float*)d_in[19];
    const float* ro_b2  = (const float*)d_in[20];
    const float* ro_w3  = (const float*)d_in[21];
    const float* ro_b3  = (const float*)d_in[22];
    float* out = (float*)d_out;

    float* h      = (float*)d_ws;
    float* x      = h + (size_t)N_NODES * H;
    float* agg    = x + (size_t)N_NODES * H;
    float* pooled = agg + (size_t)N_NODES * H;

    init_h<<<(N_NODES * (H / 4) + 255) / 256, 256, 0, stream>>>(z, emb, h);

    int rowTiles = (N_NODES + 63) / 64;  // 782
    for (int l = 0; l < LAYERS; ++l) {
        node_gemm<0><<<dim3(rowTiles, 1), 256, 0, stream>>>(
            h, cf_w1 + (size_t)l * H * H, nullptr, x, nullptr, N_NODES, H);
        hipMemsetAsync(agg, 0, (size_t)N_NODES * H * sizeof(float), stream);
        edge_kernel<<<N_EDGES / 64, 256, 0, stream>>>(
            eattr, ew, esrc, edst,
            mlp_w1 + (size_t)l * NG * H, mlp_b1 + (size_t)l * H,
            mlp_w2 + (size_t)l * H * H, mlp_b2 + (size_t)l * H, x, agg);
        node_gemm<F_BIAS><<<dim3(rowTiles, 1), 256, 0, stream>>>(
            agg, cf_w2 + (size_t)l * H * H, cf_b2 + (size_t)l * H, x, nullptr, N_NODES, H);
        node_gemm<F_BIAS | F_SSPA | F_ACCUM><<<dim3(rowTiles, 1), 256, 0, stream>>>(
            x, lin_w + (size_t)l * H * H, lin_b + (size_t)l * H, h, nullptr, N_NODES, H);
    }

    hipMemsetAsync(pooled, 0, (size_t)G_GRAPHS * 5 * H * sizeof(float), stream);
    node_gemm<F_BIAS | F_POOL><<<dim3(rowTiles, 5), 256, 0, stream>>>(
        h, ro_w1, ro_b1, pooled, batch, N_NODES, 5 * H);
    final_out<<<G_GRAPHS, 128, 0, stream>>>(pooled, ro_w2, ro_b2, ro_w3, ro_b3, out);
}

// Round 2
// 6272.325 us; speedup vs baseline: 1.0058x; 1.0058x over previous
//
#include <hip/hip_runtime.h>
#include <math.h>

#define N_NODES 50000
#define N_EDGES 1000000
#define LAYERS  3
#define G_GRAPHS 512
#define H 128
#define NG 50
#define PI_F 3.14159265358979323846f
#define LOG2_F 0.6931471805599453f

__device__ __forceinline__ float ssp(float v) {
    // softplus(x) - log(2) via hw exp/log; abs err ~1e-6, fine vs 0.4 threshold
    float t = __expf(-fabsf(v));
    return fmaxf(v, 0.0f) + __logf(1.0f + t) - LOG2_F;
}

// -------------------- h = relu(emb[z]) --------------------
__global__ __launch_bounds__(256) void init_h(const int* __restrict__ z,
                                              const float* __restrict__ emb,
                                              float* __restrict__ h) {
    int idx = blockIdx.x * 256 + threadIdx.x;          // over N*(H/4)
    if (idx >= N_NODES * (H / 4)) return;
    int n = idx >> 5;                                  // H/4 == 32
    int c4 = idx & 31;
    int zv = z[n];
    float4 v = *(const float4*)(emb + (size_t)zv * H + c4 * 4);
    v.x = fmaxf(v.x, 0.f); v.y = fmaxf(v.y, 0.f);
    v.z = fmaxf(v.z, 0.f); v.w = fmaxf(v.w, 0.f);
    *(float4*)(h + (size_t)n * H + c4 * 4) = v;
}

// -------------------- generic node GEMM: Out[n, :NC] (op) A[n,:128] @ B[128,NC] --------------------
// A-tile transposed in LDS (1 conflict-free ds_read_b128 / k-step); B read from
// global (same-address broadcast across row-groups -> L1/L2 served, keeps LDS
// port under the 85 B/cyc/CU ceiling). LDS 33.3 KB -> 4 blocks/CU.
#define F_BIAS 1
#define F_SSPA 2
#define F_ACCUM 4
#define F_POOL 8

template <int FLAGS>
__global__ __launch_bounds__(256, 4) void node_gemm(const float* __restrict__ A,
                                                    const float* __restrict__ B,
                                                    const float* __restrict__ bias,
                                                    float* __restrict__ Out,
                                                    const int* __restrict__ batch,
                                                    int nRows, int NC) {
    __shared__ float Atc[128 * 65];    // A tile transposed: [k][row], ld 65
    int tid = threadIdx.x;
    int rowBase = blockIdx.x * 64;
    int colOff = blockIdx.y * 128;
    int rlim = nRows - rowBase; if (rlim > 64) rlim = 64;

    // stage A tile transposed (coalesced 4B reads; LDS writes stride-65 = conflict-free)
    for (int idx = tid; idx < 64 * 128; idx += 256) {
        int r = idx >> 7, k = idx & 127;
        float v = 0.f;
        if (r < rlim) {
            v = A[(size_t)(rowBase + r) * H + k];
            if (FLAGS & F_SSPA) v = ssp(v);
        }
        Atc[k * 65 + r] = v;
    }
    __syncthreads();

    int cg = tid & 15, rg = tid >> 4;
    int r0 = rg * 4;
    int gc0 = colOff + cg * 4, gc1 = colOff + 64 + cg * 4;

    float acc[4][8];
#pragma unroll
    for (int j = 0; j < 4; ++j) {
        float b0 = 0.f, b1v = 0.f;
        if (FLAGS & F_BIAS) { b0 = bias[gc0 + j]; b1v = bias[gc1 + j]; }
#pragma unroll
        for (int i = 0; i < 4; ++i) { acc[i][j] = b0; acc[i][4 + j] = b1v; }
    }

#pragma unroll 4
    for (int k = 0; k < H; ++k) {
        float4 a4 = *(float4*)(Atc + k * 65 + r0);
        float4 w0 = *(const float4*)(B + (size_t)k * NC + gc0);
        float4 w1 = *(const float4*)(B + (size_t)k * NC + gc1);
        float av[4] = {a4.x, a4.y, a4.z, a4.w};
        float wv[8] = {w0.x, w0.y, w0.z, w0.w, w1.x, w1.y, w1.z, w1.w};
#pragma unroll
        for (int i = 0; i < 4; ++i)
#pragma unroll
            for (int j = 0; j < 8; ++j) acc[i][j] = fmaf(av[i], wv[j], acc[i][j]);
    }

    if (FLAGS & F_POOL) {
        // ssp, then segment-pool into Out[batch[r], :] with run compaction (batch sorted)
        int cur = -1;
        float sA[4] = {0, 0, 0, 0}, sB[4] = {0, 0, 0, 0};
#pragma unroll
        for (int i = 0; i < 4; ++i) {
            int r = r0 + i;
            int b = (r < rlim) ? batch[rowBase + r] : -1;
            if (b != cur) {
                if (cur >= 0) {
#pragma unroll
                    for (int j = 0; j < 4; ++j) {
                        unsafeAtomicAdd(Out + (size_t)cur * NC + gc0 + j, sA[j]);
                        unsafeAtomicAdd(Out + (size_t)cur * NC + gc1 + j, sB[j]);
                    }
                }
                cur = b;
#pragma unroll
                for (int j = 0; j < 4; ++j) { sA[j] = 0.f; sB[j] = 0.f; }
            }
            if (b >= 0) {
#pragma unroll
                for (int j = 0; j < 4; ++j) {
                    sA[j] += ssp(acc[i][j]);
                    sB[j] += ssp(acc[i][4 + j]);
                }
            }
        }
        if (cur >= 0) {
#pragma unroll
            for (int j = 0; j < 4; ++j) {
                unsafeAtomicAdd(Out + (size_t)cur * NC + gc0 + j, sA[j]);
                unsafeAtomicAdd(Out + (size_t)cur * NC + gc1 + j, sB[j]);
            }
        }
    } else {
#pragma unroll
        for (int i = 0; i < 4; ++i) {
            int r = r0 + i;
            if (r >= rlim) break;
            float* orow = Out + (size_t)(rowBase + r) * NC;
            float4 vA = make_float4(acc[i][0], acc[i][1], acc[i][2], acc[i][3]);
            float4 vB = make_float4(acc[i][4], acc[i][5], acc[i][6], acc[i][7]);
            if (FLAGS & F_ACCUM) {
                float4 oA = *(float4*)(orow + gc0);
                float4 oB = *(float4*)(orow + gc1);
                vA.x += oA.x; vA.y += oA.y; vA.z += oA.z; vA.w += oA.w;
                vB.x += oB.x; vB.y += oB.y; vB.z += oB.z; vB.w += oB.w;
            }
            *(float4*)(orow + gc0) = vA;
            *(float4*)(orow + gc1) = vB;
        }
    }
}

// -------------------- fused edge kernel --------------------
// Wf = (ssp(attr@W1 + b1) @ W2 + b2) * C;  agg[dst] += x[src] * Wf
// Activation tiles (attrT / Tt) in LDS; W1/W2 read from global (broadcast,
// L1/L2 served). LDS 35.6 KB -> 4 blocks/CU.
__global__ __launch_bounds__(256, 4) void edge_kernel(const float* __restrict__ eattr,
                                                      const float* __restrict__ ew,
                                                      const int* __restrict__ esrc,
                                                      const int* __restrict__ edst,
                                                      const float* __restrict__ W1,
                                                      const float* __restrict__ b1,
                                                      const float* __restrict__ W2,
                                                      const float* __restrict__ b2,
                                                      const float* __restrict__ x,
                                                      float* __restrict__ agg) {
    __shared__ float bufA[128 * 68];   // phase1: attrT[50][68]; phase2: Tt[128][68]
    __shared__ float Ce[64];
    __shared__ int Se[64], De[64];
    float* attrT = bufA;
    float* Tt = bufA;

    int tid = threadIdx.x;
    int e0 = blockIdx.x * 64;

    for (int idx = tid; idx < 64 * NG; idx += 256) {
        int e = idx / NG, k = idx - e * NG;
        attrT[k * 68 + e] = eattr[(size_t)(e0 + e) * NG + k];
    }
    if (tid < 64) {
        int e = e0 + tid;
        Ce[tid] = 0.5f * (cosf(ew[e] * (PI_F / 10.0f)) + 1.0f);
        Se[tid] = esrc[e];
        De[tid] = edst[e];
    }
    __syncthreads();

    int cg = tid & 15, rg = tid >> 4;
    int el = rg * 4;                   // 4 edges
    int c0 = cg * 4, c1 = 64 + cg * 4; // 8 cols

    // ---- GEMM1: T = ssp(attr @ W1 + b1), W1 from global (L1-resident, 25.6 KB) ----
    float acc[4][8];
#pragma unroll
    for (int j = 0; j < 4; ++j) {
        float bj0 = b1[c0 + j], bj1 = b1[c1 + j];
#pragma unroll
        for (int i = 0; i < 4; ++i) { acc[i][j] = bj0; acc[i][4 + j] = bj1; }
    }
#pragma unroll 2
    for (int k = 0; k < NG; ++k) {
        float4 av = *(float4*)(attrT + k * 68 + el);
        float4 w0 = *(const float4*)(W1 + (size_t)k * H + c0);
        float4 w1 = *(const float4*)(W1 + (size_t)k * H + c1);
        float avf[4] = {av.x, av.y, av.z, av.w};
        float wv[8] = {w0.x, w0.y, w0.z, w0.w, w1.x, w1.y, w1.z, w1.w};
#pragma unroll
        for (int i = 0; i < 4; ++i)
#pragma unroll
            for (int j = 0; j < 8; ++j) acc[i][j] = fmaf(avf[i], wv[j], acc[i][j]);
    }
    __syncthreads();   // done reading attrT; Tt overlays it
#pragma unroll
    for (int j = 0; j < 8; ++j) {
        int c = (j < 4) ? (c0 + j) : (c1 + j - 4);
        float4 tv = make_float4(ssp(acc[0][j]), ssp(acc[1][j]), ssp(acc[2][j]), ssp(acc[3][j]));
        *(float4*)(Tt + c * 68 + el) = tv;
    }
    __syncthreads();

    // ---- GEMM2: Wf = T @ W2 + b2, W2 from global (L2-resident, 64 KB) ----
    float acc2[4][8];
#pragma unroll
    for (int j = 0; j < 4; ++j) {
        float bj0 = b2[c0 + j], bj1 = b2[c1 + j];
#pragma unroll
        for (int i = 0; i < 4; ++i) { acc2[i][j] = bj0; acc2[i][4 + j] = bj1; }
    }
#pragma unroll 4
    for (int k = 0; k < H; ++k) {
        float4 tv = *(float4*)(Tt + k * 68 + el);
        float4 w0 = *(const float4*)(W2 + (size_t)k * H + c0);
        float4 w1 = *(const float4*)(W2 + (size_t)k * H + c1);
        float tvf[4] = {tv.x, tv.y, tv.z, tv.w};
        float wv[8] = {w0.x, w0.y, w0.z, w0.w, w1.x, w1.y, w1.z, w1.w};
#pragma unroll
        for (int i = 0; i < 4; ++i)
#pragma unroll
            for (int j = 0; j < 8; ++j) acc2[i][j] = fmaf(tvf[i], wv[j], acc2[i][j]);
    }

    // ---- epilogue: msg = x[src] * Wf * C -> atomic scatter to agg[dst] ----
#pragma unroll
    for (int i = 0; i < 4; ++i) {
        int le = el + i;
        float cf = Ce[le];
        int s = Se[le], d = De[le];
        float4 xa = *(const float4*)(x + (size_t)s * H + c0);
        float4 xb = *(const float4*)(x + (size_t)s * H + c1);
        float* ag = agg + (size_t)d * H;
        unsafeAtomicAdd(ag + c0 + 0, xa.x * acc2[i][0] * cf);
        unsafeAtomicAdd(ag + c0 + 1, xa.y * acc2[i][1] * cf);
        unsafeAtomicAdd(ag + c0 + 2, xa.z * acc2[i][2] * cf);
        unsafeAtomicAdd(ag + c0 + 3, xa.w * acc2[i][3] * cf);
        unsafeAtomicAdd(ag + c1 + 0, xb.x * acc2[i][4] * cf);
        unsafeAtomicAdd(ag + c1 + 1, xb.y * acc2[i][5] * cf);
        unsafeAtomicAdd(ag + c1 + 2, xb.z * acc2[i][6] * cf);
        unsafeAtomicAdd(ag + c1 + 3, xb.w * acc2[i][7] * cf);
    }
}

// -------------------- out = ssp(pooled@ro_w2 + b2) @ ro_w3 + b3 --------------------
__global__ __launch_bounds__(128) void final_out(const float* __restrict__ pooled,
                                                 const float* __restrict__ ro_w2,
                                                 const float* __restrict__ ro_b2,
                                                 const float* __restrict__ ro_w3,
                                                 const float* __restrict__ ro_b3,
                                                 float* __restrict__ out) {
    int g = blockIdx.x;
    int c = threadIdx.x;     // 128
    float acc = ro_b2[c];
    const float* pr = pooled + (size_t)g * (5 * H);
    for (int k = 0; k < 5 * H; ++k) acc = fmaf(pr[k], ro_w2[(size_t)k * H + c], acc);
    float v = ssp(acc) * ro_w3[c];
    __shared__ float red[128];
    red[c] = v;
    __syncthreads();
    for (int s = 64; s > 0; s >>= 1) {
        if (c < s) red[c] += red[c + s];
        __syncthreads();
    }
    if (c == 0) out[g] = red[0] + ro_b3[0];
}

extern "C" void kernel_launch(void* const* d_in, const int* in_sizes, int n_in,
                              void* d_out, int out_size, void* d_ws, size_t ws_size,
                              hipStream_t stream) {
    const int* z     = (const int*)d_in[0];
    const int* esrc  = (const int*)d_in[1];
    const int* edst  = (const int*)d_in[2];
    const int* batch = (const int*)d_in[3];
    const float* ew    = (const float*)d_in[5];
    const float* eattr = (const float*)d_in[6];
    const float* emb   = (const float*)d_in[7];
    const float* mlp_w1 = (const float*)d_in[8];
    const float* mlp_b1 = (const float*)d_in[9];
    const float* mlp_w2 = (const float*)d_in[10];
    const float* mlp_b2 = (const float*)d_in[11];
    const float* cf_w1  = (const float*)d_in[12];
    const float* cf_w2  = (const float*)d_in[13];
    const float* cf_b2  = (const float*)d_in[14];
    const float* lin_w  = (const float*)d_in[15];
    const float* lin_b  = (const float*)d_in[16];
    const float* ro_w1  = (const float*)d_in[17];
    const float* ro_b1  = (const float*)d_in[18];
    const float* ro_w2  = (const float*)d_in[19];
    const float* ro_b2  = (const float*)d_in[20];
    const float* ro_w3  = (const float*)d_in[21];
    const float* ro_b3  = (const float*)d_in[22];
    float* out = (float*)d_out;

    float* h      = (float*)d_ws;
    float* x      = h + (size_t)N_NODES * H;
    float* agg    = x + (size_t)N_NODES * H;
    float* pooled = agg + (size_t)N_NODES * H;

    init_h<<<(N_NODES * (H / 4) + 255) / 256, 256, 0, stream>>>(z, emb, h);

    int rowTiles = (N_NODES + 63) / 64;  // 782
    for (int l = 0; l < LAYERS; ++l) {
        node_gemm<0><<<dim3(rowTiles, 1), 256, 0, stream>>>(
            h, cf_w1 + (size_t)l * H * H, nullptr, x, nullptr, N_NODES, H);
        hipMemsetAsync(agg, 0, (size_t)N_NODES * H * sizeof(float), stream);
        edge_kernel<<<N_EDGES / 64, 256, 0, stream>>>(
            eattr, ew, esrc, edst,
            mlp_w1 + (size_t)l * NG * H, mlp_b1 + (size_t)l * H,
            mlp_w2 + (size_t)l * H * H, mlp_b2 + (size_t)l * H, x, agg);
        node_gemm<F_BIAS><<<dim3(rowTiles, 1), 256, 0, stream>>>(
            agg, cf_w2 + (size_t)l * H * H, cf_b2 + (size_t)l * H, x, nullptr, N_NODES, H);
        node_gemm<F_BIAS | F_SSPA | F_ACCUM><<<dim3(rowTiles, 1), 256, 0, stream>>>(
            x, lin_w + (size_t)l * H * H, lin_b + (size_t)l * H, h, nullptr, N_NODES, H);
    }

    hipMemsetAsync(pooled, 0, (size_t)G_GRAPHS * 5 * H * sizeof(float), stream);
    node_gemm<F_BIAS | F_POOL><<<dim3(rowTiles, 5), 256, 0, stream>>>(
        h, ro_w1, ro_b1, pooled, batch, N_NODES, 5 * H);
    final_out<<<G_GRAPHS, 128, 0, stream>>>(pooled, ro_w2, ro_b2, ro_w3, ro_b3, out);
}

// Round 3
// 3855.255 us; speedup vs baseline: 1.6363x; 1.6270x over previous
//
#include <hip/hip_runtime.h>
#include <math.h>

#define N_NODES 50000
#define N_EDGES 1000000
#define LAYERS  3
#define G_GRAPHS 512
#define H 128
#define NG 50
#define PI_F 3.14159265358979323846f
#define LOG2_F 0.6931471805599453f

__device__ __forceinline__ float ssp(float v) {
    // softplus(x) - log(2) via hw exp/log; abs err ~1e-6, fine vs 0.4 threshold
    float t = __expf(-fabsf(v));
    return fmaxf(v, 0.0f) + __logf(1.0f + t) - LOG2_F;
}

// -------------------- h = relu(emb[z]) --------------------
__global__ __launch_bounds__(256) void init_h(const int* __restrict__ z,
                                              const float* __restrict__ emb,
                                              float* __restrict__ h) {
    int idx = blockIdx.x * 256 + threadIdx.x;          // over N*(H/4)
    if (idx >= N_NODES * (H / 4)) return;
    int n = idx >> 5;                                  // H/4 == 32
    int c4 = idx & 31;
    int zv = z[n];
    float4 v = *(const float4*)(emb + (size_t)zv * H + c4 * 4);
    v.x = fmaxf(v.x, 0.f); v.y = fmaxf(v.y, 0.f);
    v.z = fmaxf(v.z, 0.f); v.w = fmaxf(v.w, 0.f);
    *(float4*)(h + (size_t)n * H + c4 * 4) = v;
}

// -------------------- CSR build: sort edges by dst --------------------
__global__ __launch_bounds__(256) void hist_kernel(const int* __restrict__ edst,
                                                   int* __restrict__ cnt) {
    int e = blockIdx.x * 256 + threadIdx.x;
    if (e < N_EDGES) atomicAdd(&cnt[edst[e]], 1);
}

// single-block exclusive scan: cur[d] = sum_{d'<d} cnt[d']
__global__ __launch_bounds__(1024) void scan_kernel(const int* __restrict__ cnt,
                                                    int* __restrict__ cur) {
    __shared__ int buf[1024];
    __shared__ int carry;
    int tid = threadIdx.x;
    if (tid == 0) carry = 0;
    __syncthreads();
    for (int base = 0; base < N_NODES; base += 1024) {
        int i = base + tid;
        int v = (i < N_NODES) ? cnt[i] : 0;
        int incl = v;
        buf[tid] = incl;
        __syncthreads();
        for (int s = 1; s < 1024; s <<= 1) {
            int t = (tid >= s) ? buf[tid - s] : 0;
            __syncthreads();
            incl += t;
            buf[tid] = incl;
            __syncthreads();
        }
        int cbase = carry;
        if (i < N_NODES) cur[i] = cbase + incl - v;
        __syncthreads();
        if (tid == 1023) carry = cbase + incl;
        __syncthreads();
    }
}

__global__ __launch_bounds__(256) void scatter_kernel(const int* __restrict__ edst,
                                                      int* __restrict__ cur,
                                                      int* __restrict__ perm) {
    int e = blockIdx.x * 256 + threadIdx.x;
    if (e < N_EDGES) {
        int p = atomicAdd(&cur[edst[e]], 1);
        perm[p] = e;
    }
}

// -------------------- generic node GEMM: Out[n, :NC] (op) A[n,:128] @ B[128,NC] --------------------
#define F_BIAS 1
#define F_SSPA 2
#define F_ACCUM 4
#define F_POOL 8

template <int FLAGS>
__global__ __launch_bounds__(256, 4) void node_gemm(const float* __restrict__ A,
                                                    const float* __restrict__ B,
                                                    const float* __restrict__ bias,
                                                    float* __restrict__ Out,
                                                    const int* __restrict__ batch,
                                                    int nRows, int NC) {
    __shared__ float Atc[128 * 65];    // A tile transposed: [k][row], ld 65
    int tid = threadIdx.x;
    int rowBase = blockIdx.x * 64;
    int colOff = blockIdx.y * 128;
    int rlim = nRows - rowBase; if (rlim > 64) rlim = 64;

    for (int idx = tid; idx < 64 * 128; idx += 256) {
        int r = idx >> 7, k = idx & 127;
        float v = 0.f;
        if (r < rlim) {
            v = A[(size_t)(rowBase + r) * H + k];
            if (FLAGS & F_SSPA) v = ssp(v);
        }
        Atc[k * 65 + r] = v;
    }
    __syncthreads();

    int cg = tid & 15, rg = tid >> 4;
    int r0 = rg * 4;
    int gc0 = colOff + cg * 4, gc1 = colOff + 64 + cg * 4;

    float acc[4][8];
#pragma unroll
    for (int j = 0; j < 4; ++j) {
        float b0 = 0.f, b1v = 0.f;
        if (FLAGS & F_BIAS) { b0 = bias[gc0 + j]; b1v = bias[gc1 + j]; }
#pragma unroll
        for (int i = 0; i < 4; ++i) { acc[i][j] = b0; acc[i][4 + j] = b1v; }
    }

#pragma unroll 4
    for (int k = 0; k < H; ++k) {
        float4 a4 = *(float4*)(Atc + k * 65 + r0);
        float4 w0 = *(const float4*)(B + (size_t)k * NC + gc0);
        float4 w1 = *(const float4*)(B + (size_t)k * NC + gc1);
        float av[4] = {a4.x, a4.y, a4.z, a4.w};
        float wv[8] = {w0.x, w0.y, w0.z, w0.w, w1.x, w1.y, w1.z, w1.w};
#pragma unroll
        for (int i = 0; i < 4; ++i)
#pragma unroll
            for (int j = 0; j < 8; ++j) acc[i][j] = fmaf(av[i], wv[j], acc[i][j]);
    }

    if (FLAGS & F_POOL) {
        int cur = -1;
        float sA[4] = {0, 0, 0, 0}, sB[4] = {0, 0, 0, 0};
#pragma unroll
        for (int i = 0; i < 4; ++i) {
            int r = r0 + i;
            int b = (r < rlim) ? batch[rowBase + r] : -1;
            if (b != cur) {
                if (cur >= 0) {
#pragma unroll
                    for (int j = 0; j < 4; ++j) {
                        unsafeAtomicAdd(Out + (size_t)cur * NC + gc0 + j, sA[j]);
                        unsafeAtomicAdd(Out + (size_t)cur * NC + gc1 + j, sB[j]);
                    }
                }
                cur = b;
#pragma unroll
                for (int j = 0; j < 4; ++j) { sA[j] = 0.f; sB[j] = 0.f; }
            }
            if (b >= 0) {
#pragma unroll
                for (int j = 0; j < 4; ++j) {
                    sA[j] += ssp(acc[i][j]);
                    sB[j] += ssp(acc[i][4 + j]);
                }
            }
        }
        if (cur >= 0) {
#pragma unroll
            for (int j = 0; j < 4; ++j) {
                unsafeAtomicAdd(Out + (size_t)cur * NC + gc0 + j, sA[j]);
                unsafeAtomicAdd(Out + (size_t)cur * NC + gc1 + j, sB[j]);
            }
        }
    } else {
#pragma unroll
        for (int i = 0; i < 4; ++i) {
            int r = r0 + i;
            if (r >= rlim) break;
            float* orow = Out + (size_t)(rowBase + r) * NC;
            float4 vA = make_float4(acc[i][0], acc[i][1], acc[i][2], acc[i][3]);
            float4 vB = make_float4(acc[i][4], acc[i][5], acc[i][6], acc[i][7]);
            if (FLAGS & F_ACCUM) {
                float4 oA = *(float4*)(orow + gc0);
                float4 oB = *(float4*)(orow + gc1);
                vA.x += oA.x; vA.y += oA.y; vA.z += oA.z; vA.w += oA.w;
                vB.x += oB.x; vB.y += oB.y; vB.z += oB.z; vB.w += oB.w;
            }
            *(float4*)(orow + gc0) = vA;
            *(float4*)(orow + gc1) = vB;
        }
    }
}

// -------------------- fused edge kernel, dst-sorted --------------------
// Processes edges in dst-sorted order (perm). Wf = (ssp(attr@W1+b1)@W2+b2)*C;
// msg = x[src]*Wf accumulated per dst-run in LDS (ds_add_f32), then ONE plain
// coalesced store per complete run (sole writer); global atomics only for the
// <=2 runs that cross block boundaries. Kills the 2 GB random atomic traffic.
__global__ __launch_bounds__(256, 4) void edge_kernel(const float* __restrict__ eattr,
                                                      const float* __restrict__ ew,
                                                      const int* __restrict__ esrc,
                                                      const int* __restrict__ edst,
                                                      const int* __restrict__ perm,
                                                      const float* __restrict__ W1,
                                                      const float* __restrict__ b1,
                                                      const float* __restrict__ W2,
                                                      const float* __restrict__ b2,
                                                      const float* __restrict__ x,
                                                      float* __restrict__ agg) {
    __shared__ float bufA[128 * 68];   // attrT[50][68] -> Tt[128][68] -> accT[64][132]
    __shared__ float Ce[64];
    __shared__ int Se[64], De[64], Ge[64], Rid[64], RunDst[64];
    __shared__ int s_bound[2];         // prev dst, next dst
    float* attrT = bufA;
    float* Tt = bufA;
    float* accT = bufA;

    int tid = threadIdx.x;
    int e0 = blockIdx.x * 64;

    if (tid < 64) {
        int ge = perm[e0 + tid];
        Ge[tid] = ge;
        Se[tid] = esrc[ge];
        De[tid] = edst[ge];
        Ce[tid] = 0.5f * (cosf(ew[ge] * (PI_F / 10.0f)) + 1.0f);
    }
    if (tid == 64) s_bound[0] = (e0 > 0) ? edst[perm[e0 - 1]] : -1;
    if (tid == 65) s_bound[1] = (e0 + 64 < N_EDGES) ? edst[perm[e0 + 64]] : -1;
    __syncthreads();

    for (int idx = tid; idx < 64 * NG; idx += 256) {
        int e = idx / NG, k = idx - e * NG;
        attrT[k * 68 + e] = eattr[(size_t)Ge[e] * NG + k];
    }
    // run-id scan over the sorted dst list (wave 0 only; consumed after barriers)
    if (tid < 64) {
        int f = (tid > 0 && De[tid] != De[tid - 1]) ? 1 : 0;
#pragma unroll
        for (int s = 1; s < 64; s <<= 1) {
            int o = __shfl_up(f, s, 64);
            if (tid >= s) f += o;
        }
        Rid[tid] = f;
        RunDst[f] = De[tid];
    }
    __syncthreads();

    int cg = tid & 15, rg = tid >> 4;
    int el = rg * 4;                   // 4 consecutive sorted edges
    int c0 = cg * 4, c1 = 64 + cg * 4; // 8 cols

    // ---- GEMM1: T = ssp(attr @ W1 + b1), W1 from global (L1-resident) ----
    float acc[4][8];
#pragma unroll
    for (int j = 0; j < 4; ++j) {
        float bj0 = b1[c0 + j], bj1 = b1[c1 + j];
#pragma unroll
        for (int i = 0; i < 4; ++i) { acc[i][j] = bj0; acc[i][4 + j] = bj1; }
    }
#pragma unroll 2
    for (int k = 0; k < NG; ++k) {
        float4 av = *(float4*)(attrT + k * 68 + el);
        float4 w0 = *(const float4*)(W1 + (size_t)k * H + c0);
        float4 w1 = *(const float4*)(W1 + (size_t)k * H + c1);
        float avf[4] = {av.x, av.y, av.z, av.w};
        float wv[8] = {w0.x, w0.y, w0.z, w0.w, w1.x, w1.y, w1.z, w1.w};
#pragma unroll
        for (int i = 0; i < 4; ++i)
#pragma unroll
            for (int j = 0; j < 8; ++j) acc[i][j] = fmaf(avf[i], wv[j], acc[i][j]);
    }
    __syncthreads();   // done reading attrT; Tt overlays it
#pragma unroll
    for (int j = 0; j < 8; ++j) {
        int c = (j < 4) ? (c0 + j) : (c1 + j - 4);
        float4 tv = make_float4(ssp(acc[0][j]), ssp(acc[1][j]), ssp(acc[2][j]), ssp(acc[3][j]));
        *(float4*)(Tt + c * 68 + el) = tv;
    }
    __syncthreads();

    // ---- GEMM2: Wf = T @ W2 + b2, W2 from global (L2-resident) ----
    float acc2[4][8];
#pragma unroll
    for (int j = 0; j < 4; ++j) {
        float bj0 = b2[c0 + j], bj1 = b2[c1 + j];
#pragma unroll
        for (int i = 0; i < 4; ++i) { acc2[i][j] = bj0; acc2[i][4 + j] = bj1; }
    }
#pragma unroll 4
    for (int k = 0; k < H; ++k) {
        float4 tv = *(float4*)(Tt + k * 68 + el);
        float4 w0 = *(const float4*)(W2 + (size_t)k * H + c0);
        float4 w1 = *(const float4*)(W2 + (size_t)k * H + c1);
        float tvf[4] = {tv.x, tv.y, tv.z, tv.w};
        float wv[8] = {w0.x, w0.y, w0.z, w0.w, w1.x, w1.y, w1.z, w1.w};
#pragma unroll
        for (int i = 0; i < 4; ++i)
#pragma unroll
            for (int j = 0; j < 8; ++j) acc2[i][j] = fmaf(tvf[i], wv[j], acc2[i][j]);
    }
    __syncthreads();   // all lanes done reading Tt; accT overlays it

    // ---- epilogue: per-run LDS accumulation, then one store per run ----
    int nruns = Rid[63] + 1;
    for (int idx = tid; idx < nruns * 132; idx += 256) accT[idx] = 0.f;
    __syncthreads();

    int curR = -1;
    float part[8];
#pragma unroll
    for (int i = 0; i < 4; ++i) {
        int le = el + i;
        int r = Rid[le];
        float cf = Ce[le];
        int s = Se[le];
        float4 xa = *(const float4*)(x + (size_t)s * H + c0);
        float4 xb = *(const float4*)(x + (size_t)s * H + c1);
        float m[8] = {xa.x * acc2[i][0] * cf, xa.y * acc2[i][1] * cf,
                      xa.z * acc2[i][2] * cf, xa.w * acc2[i][3] * cf,
                      xb.x * acc2[i][4] * cf, xb.y * acc2[i][5] * cf,
                      xb.z * acc2[i][6] * cf, xb.w * acc2[i][7] * cf};
        if (r != curR) {
            if (curR >= 0) {
#pragma unroll
                for (int j = 0; j < 4; ++j) {
                    atomicAdd(accT + curR * 132 + c0 + j, part[j]);
                    atomicAdd(accT + curR * 132 + c1 + j, part[4 + j]);
                }
            }
            curR = r;
#pragma unroll
            for (int j = 0; j < 8; ++j) part[j] = m[j];
        } else {
#pragma unroll
            for (int j = 0; j < 8; ++j) part[j] += m[j];
        }
    }
#pragma unroll
    for (int j = 0; j < 4; ++j) {
        atomicAdd(accT + curR * 132 + c0 + j, part[j]);
        atomicAdd(accT + curR * 132 + c1 + j, part[4 + j]);
    }
    __syncthreads();

    int prevd = s_bound[0], nextd = s_bound[1];
    for (int idx = tid; idx < nruns * H; idx += 256) {
        int r = idx >> 7, c = idx & 127;
        float v = accT[r * 132 + c];
        int d = RunDst[r];
        bool shared_run = (r == 0 && d == prevd) || (r == nruns - 1 && d == nextd);
        float* p = agg + (size_t)d * H + c;
        if (shared_run) unsafeAtomicAdd(p, v);
        else *p = v;                    // sole writer: plain coalesced store
    }
}

// -------------------- out = ssp(pooled@ro_w2 + b2) @ ro_w3 + b3 --------------------
__global__ __launch_bounds__(128) void final_out(const float* __restrict__ pooled,
                                                 const float* __restrict__ ro_w2,
                                                 const float* __restrict__ ro_b2,
                                                 const float* __restrict__ ro_w3,
                                                 const float* __restrict__ ro_b3,
                                                 float* __restrict__ out) {
    int g = blockIdx.x;
    int c = threadIdx.x;     // 128
    float acc = ro_b2[c];
    const float* pr = pooled + (size_t)g * (5 * H);
    for (int k = 0; k < 5 * H; ++k) acc = fmaf(pr[k], ro_w2[(size_t)k * H + c], acc);
    float v = ssp(acc) * ro_w3[c];
    __shared__ float red[128];
    red[c] = v;
    __syncthreads();
    for (int s = 64; s > 0; s >>= 1) {
        if (c < s) red[c] += red[c + s];
        __syncthreads();
    }
    if (c == 0) out[g] = red[0] + ro_b3[0];
}

extern "C" void kernel_launch(void* const* d_in, const int* in_sizes, int n_in,
                              void* d_out, int out_size, void* d_ws, size_t ws_size,
                              hipStream_t stream) {
    const int* z     = (const int*)d_in[0];
    const int* esrc  = (const int*)d_in[1];
    const int* edst  = (const int*)d_in[2];
    const int* batch = (const int*)d_in[3];
    const float* ew    = (const float*)d_in[5];
    const float* eattr = (const float*)d_in[6];
    const float* emb   = (const float*)d_in[7];
    const float* mlp_w1 = (const float*)d_in[8];
    const float* mlp_b1 = (const float*)d_in[9];
    const float* mlp_w2 = (const float*)d_in[10];
    const float* mlp_b2 = (const float*)d_in[11];
    const float* cf_w1  = (const float*)d_in[12];
    const float* cf_w2  = (const float*)d_in[13];
    const float* cf_b2  = (const float*)d_in[14];
    const float* lin_w  = (const float*)d_in[15];
    const float* lin_b  = (const float*)d_in[16];
    const float* ro_w1  = (const float*)d_in[17];
    const float* ro_b1  = (const float*)d_in[18];
    const float* ro_w2  = (const float*)d_in[19];
    const float* ro_b2  = (const float*)d_in[20];
    const float* ro_w3  = (const float*)d_in[21];
    const float* ro_b3  = (const float*)d_in[22];
    float* out = (float*)d_out;

    float* h      = (float*)d_ws;
    float* x      = h + (size_t)N_NODES * H;
    float* agg    = x + (size_t)N_NODES * H;
    float* pooled = agg + (size_t)N_NODES * H;
    int*   cnt    = (int*)(pooled + (size_t)G_GRAPHS * 5 * H);
    int*   cur    = cnt + N_NODES;
    int*   perm   = cur + N_NODES;

    init_h<<<(N_NODES * (H / 4) + 255) / 256, 256, 0, stream>>>(z, emb, h);

    // CSR build (once; reused by all 3 layers)
    hipMemsetAsync(cnt, 0, N_NODES * sizeof(int), stream);
    hist_kernel<<<(N_EDGES + 255) / 256, 256, 0, stream>>>(edst, cnt);
    scan_kernel<<<1, 1024, 0, stream>>>(cnt, cur);
    scatter_kernel<<<(N_EDGES + 255) / 256, 256, 0, stream>>>(edst, cur, perm);

    int rowTiles = (N_NODES + 63) / 64;  // 782
    for (int l = 0; l < LAYERS; ++l) {
        node_gemm<0><<<dim3(rowTiles, 1), 256, 0, stream>>>(
            h, cf_w1 + (size_t)l * H * H, nullptr, x, nullptr, N_NODES, H);
        hipMemsetAsync(agg, 0, (size_t)N_NODES * H * sizeof(float), stream);
        edge_kernel<<<N_EDGES / 64, 256, 0, stream>>>(
            eattr, ew, esrc, edst, perm,
            mlp_w1 + (size_t)l * NG * H, mlp_b1 + (size_t)l * H,
            mlp_w2 + (size_t)l * H * H, mlp_b2 + (size_t)l * H, x, agg);
        node_gemm<F_BIAS><<<dim3(rowTiles, 1), 256, 0, stream>>>(
            agg, cf_w2 + (size_t)l * H * H, cf_b2 + (size_t)l * H, x, nullptr, N_NODES, H);
        node_gemm<F_BIAS | F_SSPA | F_ACCUM><<<dim3(rowTiles, 1), 256, 0, stream>>>(
            x, lin_w + (size_t)l * H * H, lin_b + (size_t)l * H, h, nullptr, N_NODES, H);
    }

    hipMemsetAsync(pooled, 0, (size_t)G_GRAPHS * 5 * H * sizeof(float), stream);
    node_gemm<F_BIAS | F_POOL><<<dim3(rowTiles, 5), 256, 0, stream>>>(
        h, ro_w1, ro_b1, pooled, batch, N_NODES, 5 * H);
    final_out<<<G_GRAPHS, 128, 0, stream>>>(pooled, ro_w2, ro_b2, ro_w3, ro_b3, out);
}